// Round 1
// baseline (593.208 us; speedup 1.0000x reference)
//
#include <hip/hip_runtime.h>

#define NB 4
#define NS 1024
#define NH 256
#define NR 65536
#define NF 768
#define NK 512

typedef __attribute__((ext_vector_type(8))) short bf16x8;
typedef __attribute__((ext_vector_type(4))) float f32x4;

static __device__ __forceinline__ unsigned short f2bf(float f) {
  unsigned int u = __builtin_bit_cast(unsigned int, f);
  u += 0x7FFFu + ((u >> 16) & 1u);   // RTNE
  return (unsigned short)(u >> 16);
}

// rel_ids may arrive as int32 or int64. Values are in [0,1024), so if int64,
// every odd int32 word (the high half) is zero. Sample 8192 odd words.
__global__ void detect_idw(const int* __restrict__ ids, int* __restrict__ flag) {
  __shared__ int anynz;
  if (threadIdx.x == 0) anynz = 0;
  __syncthreads();
  int acc = 0;
  for (int i = threadIdx.x; i < 8192; i += 256) acc |= ids[2 * i + 1];
  if (acc != 0) atomicOr(&anynz, 1);
  __syncthreads();
  if (threadIdx.x == 0) flag[0] = (anynz == 0) ? 1 : 0;  // 1 => int64 layout
}

// W1 (512x768) f32 -> W1T (768x512) bf16
__global__ void prep_w1(const float* __restrict__ w1, unsigned short* __restrict__ w1t) {
  int i = blockIdx.x * 256 + threadIdx.x;   // 768*512 = 393216
  int n = i >> 9, k = i & 511;
  w1t[i] = f2bf(w1[k * NF + n]);
}

// W2 (768x256) f32 -> W2T (256x768) bf16
__global__ void prep_w2(const float* __restrict__ w2, unsigned short* __restrict__ w2t) {
  int i = blockIdx.x * 256 + threadIdx.x;   // 256*768 = 196608
  int n = i / NF, k = i - n * NF;
  w2t[i] = f2bf(w2[k * NH + n]);
}

// Fused: gather -> GEMM1(relu,+b1) -> GEMM2(+b2), 64 rows per block, 4 waves.
__global__ __launch_bounds__(256, 2)
void fused_relffn(const float* __restrict__ span, const int* __restrict__ ids,
                  const float* __restrict__ b1, const float* __restrict__ b2,
                  const unsigned short* __restrict__ w1t,
                  const unsigned short* __restrict__ w2t,
                  const int* __restrict__ flagp, float* __restrict__ out) {
  __shared__ __align__(16) unsigned short As[64 * 512];  // 64 KB, swizzled
  __shared__ __align__(16) unsigned short Hs[64 * 128];  // 16 KB, swizzled

  const int tid = threadIdx.x;
  const int blk = blockIdx.x;
  const int bb = blk >> 10;              // batch
  const int r0 = (blk & 1023) << 6;      // first relation row
  const int lane = tid & 63;
  const int w = tid >> 6;                // wave 0..3
  const int l15 = lane & 15;
  const int lq = lane >> 4;              // 0..3
  const int is64 = flagp[0];

  // ---- gather A tile: 64 rows x 512 (head|tail), f32 -> bf16, swizzled ----
  {
    const long pair0 = ((long)bb * NR + r0) * 2;
#pragma unroll
    for (int j = 0; j < 16; ++j) {
      int g = tid + j * 256;             // 0..4095 chunk id
      int row = g >> 6;                  // 0..63
      int kc = g & 63;                   // 8-float chunk within row
      long pidx = pair0 + row * 2 + (kc >> 5);     // head / tail id slot
      int id = is64 ? ids[pidx * 2] : ids[pidx];
      const float* src = span + ((size_t)bb * NS + id) * NH + (kc & 31) * 8;
      float4 v0 = *(const float4*)src;
      float4 v1 = *(const float4*)(src + 4);
      uint4 pk;
      pk.x = f2bf(v0.x) | ((unsigned)f2bf(v0.y) << 16);
      pk.y = f2bf(v0.z) | ((unsigned)f2bf(v0.w) << 16);
      pk.z = f2bf(v1.x) | ((unsigned)f2bf(v1.y) << 16);
      pk.w = f2bf(v1.z) | ((unsigned)f2bf(v1.w) << 16);
      int idx = row * 512 + ((kc * 8) ^ ((row & 7) << 3));  // XOR swizzle (16B units)
      *(uint4*)&As[idx] = pk;
    }
  }
  __syncthreads();

  f32x4 acc2[4][4];
#pragma unroll
  for (int mi = 0; mi < 4; ++mi)
#pragma unroll
    for (int nj = 0; nj < 4; ++nj) {
      f32x4 z = {0.f, 0.f, 0.f, 0.f};
      acc2[mi][nj] = z;
    }

  for (int c = 0; c < 6; ++c) {
    // ---- GEMM1: h-slice (64 x 128) = A(64x512) @ W1[:, c*128:+128], swapped
    // operands: D[n][m] = mfma(A=W1T frag, B=As frag) ----
    f32x4 acc1[4][2];
#pragma unroll
    for (int mi = 0; mi < 4; ++mi)
#pragma unroll
      for (int ni = 0; ni < 2; ++ni) {
        f32x4 z = {0.f, 0.f, 0.f, 0.f};
        acc1[mi][ni] = z;
      }
    const unsigned short* w1p = w1t + ((c * 128 + w * 32 + l15) * NK + lq * 8);
#pragma unroll 4
    for (int kk = 0; kk < 16; ++kk) {
      bf16x8 wf0 = *(const bf16x8*)(w1p + kk * 32);
      bf16x8 wf1 = *(const bf16x8*)(w1p + 16 * NK + kk * 32);
      bf16x8 af[4];
#pragma unroll
      for (int mi = 0; mi < 4; ++mi) {
        int row = mi * 16 + l15;
        int kidx = kk * 32 + lq * 8;
        af[mi] = *(const bf16x8*)&As[row * 512 + (kidx ^ ((row & 7) << 3))];
      }
#pragma unroll
      for (int mi = 0; mi < 4; ++mi) {
        acc1[mi][0] = __builtin_amdgcn_mfma_f32_16x16x32_bf16(wf0, af[mi], acc1[mi][0], 0, 0, 0);
        acc1[mi][1] = __builtin_amdgcn_mfma_f32_16x16x32_bf16(wf1, af[mi], acc1[mi][1], 0, 0, 0);
      }
    }
    __syncthreads();   // prior chunk's Hs reads done before overwrite
    // bias + relu + bf16 pack; lane holds 4 consecutive n for fixed m
#pragma unroll
    for (int ni = 0; ni < 2; ++ni) {
      int n0 = c * 128 + w * 32 + ni * 16 + lq * 4;
      float4 bv = *(const float4*)(b1 + n0);
#pragma unroll
      for (int mi = 0; mi < 4; ++mi) {
        f32x4 a = acc1[mi][ni];
        float x0 = fmaxf(a[0] + bv.x, 0.0f);
        float x1 = fmaxf(a[1] + bv.y, 0.0f);
        float x2 = fmaxf(a[2] + bv.z, 0.0f);
        float x3 = fmaxf(a[3] + bv.w, 0.0f);
        int m = mi * 16 + l15;
        int nl0 = w * 32 + ni * 16 + lq * 4;
        uint2 pk;
        pk.x = f2bf(x0) | ((unsigned)f2bf(x1) << 16);
        pk.y = f2bf(x2) | ((unsigned)f2bf(x3) << 16);
        *(uint2*)&Hs[m * 128 + (nl0 ^ ((m & 7) << 3))] = pk;
      }
    }
    __syncthreads();
    // ---- GEMM2 partial: acc2 += W2[c*128:+128, :] (as W2T frags) @ h-slice ----
    const unsigned short* w2p = w2t + ((w * 64 + l15) * NF + c * 128 + lq * 8);
#pragma unroll
    for (int kq = 0; kq < 4; ++kq) {
      bf16x8 vf[4];
#pragma unroll
      for (int nj = 0; nj < 4; ++nj)
        vf[nj] = *(const bf16x8*)(w2p + nj * 16 * NF + kq * 32);
      bf16x8 hf[4];
#pragma unroll
      for (int mi = 0; mi < 4; ++mi) {
        int row = mi * 16 + l15;
        int kidx = kq * 32 + lq * 8;
        hf[mi] = *(const bf16x8*)&Hs[row * 128 + (kidx ^ ((row & 7) << 3))];
      }
#pragma unroll
      for (int mi = 0; mi < 4; ++mi)
#pragma unroll
        for (int nj = 0; nj < 4; ++nj)
          acc2[mi][nj] = __builtin_amdgcn_mfma_f32_16x16x32_bf16(vf[nj], hf[mi], acc2[mi][nj], 0, 0, 0);
    }
  }

  // ---- epilogue: +b2, float4 stores (lane owns 4 consecutive nout) ----
#pragma unroll
  for (int nj = 0; nj < 4; ++nj) {
    int n0 = w * 64 + nj * 16 + lq * 4;
    float4 bv = *(const float4*)(b2 + n0);
#pragma unroll
    for (int mi = 0; mi < 4; ++mi) {
      int m = mi * 16 + l15;
      f32x4 a = acc2[mi][nj];
      float4 o;
      o.x = a[0] + bv.x; o.y = a[1] + bv.y; o.z = a[2] + bv.z; o.w = a[3] + bv.w;
      *(float4*)(out + ((size_t)bb * NR + r0 + m) * NH + n0) = o;
    }
  }
}

extern "C" void kernel_launch(void* const* d_in, const int* in_sizes, int n_in,
                              void* d_out, int out_size, void* d_ws, size_t ws_size,
                              hipStream_t stream) {
  const float* span = (const float*)d_in[0];
  const int* ids = (const int*)d_in[1];
  const float* W1 = (const float*)d_in[2];
  const float* b1 = (const float*)d_in[3];
  const float* W2 = (const float*)d_in[4];
  const float* b2 = (const float*)d_in[5];
  float* out = (float*)d_out;

  char* ws = (char*)d_ws;
  int* flag = (int*)ws;
  unsigned short* w1t = (unsigned short*)(ws + 64);                    // 768x512 bf16
  unsigned short* w2t = (unsigned short*)(ws + 64 + NF * NK * 2);      // 256x768 bf16

  detect_idw<<<1, 256, 0, stream>>>(ids, flag);
  prep_w1<<<(NF * NK) / 256, 256, 0, stream>>>(W1, w1t);
  prep_w2<<<(NH * NF) / 256, 256, 0, stream>>>(W2, w2t);
  fused_relffn<<<4096, 256, 0, stream>>>(span, ids, b1, b2, w1t, w2t, flag, out);
}